// Round 9
// baseline (267.783 us; speedup 1.0000x reference)
//
#include <hip/hip_runtime.h>
#include <hip/hip_bf16.h>

#define B_SZ 32
#define T_TOK 1024
#define H_DIM 256
#define T_MEL 4096
#define K_SZ 5
#define BM 64
#define ROWS (BM + 4)          // 68 staged x rows
#define XS_BYTES (ROWS * 512)  // 34816
#define NCONV 512
#define NEXP 1024              // 128 frames per expand unit
#define NUNITS (NCONV + NEXP)

typedef __attribute__((ext_vector_type(8))) short bf16x8;
typedef __attribute__((ext_vector_type(4))) float f32x4;

__device__ inline short f2bf(float f) {
    __hip_bfloat16 h = __float2bfloat16(f);
    return *reinterpret_cast<short*>(&h);
}

// ---- prep: repack W (blocks 0..159) + scan+tokmap scatter (blocks 160..191) ----
// W repack: [H_out][H_in][K] f32 -> bf16 B-fragment order [s][n16][lane][j]
__global__ __launch_bounds__(256) void prep_kernel(const float* __restrict__ w,
                                                   short* __restrict__ wr,
                                                   const float* __restrict__ a,
                                                   const int* __restrict__ gt,
                                                   float* __restrict__ acc,
                                                   int* __restrict__ tokmap,
                                                   int* __restrict__ ctrs) {
    __shared__ float s_c[T_TOK];
    if (blockIdx.x < 160) {
        int idx = blockIdx.x * 256 + threadIdx.x;   // 40*16*64 threads
        int lane = idx & 63;
        int n = (idx >> 6) & 15;
        int s = idx >> 10;
        int k = s >> 3;
        int hi0 = (s & 7) * 32 + (lane >> 4) * 8;
        int ho = n * 16 + (lane & 15);
        short out[8];
#pragma unroll
        for (int j = 0; j < 8; ++j)
            out[j] = f2bf(w[(ho * H_DIM + hi0 + j) * K_SZ + k]);
        *reinterpret_cast<bf16x8*>(wr + (size_t)idx * 8) = *reinterpret_cast<bf16x8*>(out);
        return;
    }
    int b = blockIdx.x - 160;
    int tid = threadIdx.x;
    if (tid == 1) acc[b] = 0.f;                     // reset exp-sum accumulator
    if (b == 0 && tid == 2) { ctrs[0] = 0; ctrs[1] = 0; }   // work + done counters
    ((float4*)s_c)[tid] = ((const float4*)(a + b * T_TOK))[tid];
    __syncthreads();
    if (tid == 0) {
        float c = 0.f;
        float lim = (float)gt[b];
        for (int t = 0; t < T_TOK; ++t) {           // matches np.cumsum order
            c += s_c[t];
            s_c[t] = fminf(c, lim);
        }
    }
    __syncthreads();
    // token t owns frames [ceil(c[t-1]), ceil(c[t]))  (contiguous partition)
    int* tm = tokmap + b * T_MEL;
    for (int t = tid; t < T_TOK; t += 256) {
        float c1 = s_c[t];
        float c0 = (t == 0) ? 0.f : s_c[t - 1];
        int f0 = (int)ceilf(c0);
        int f1 = (int)ceilf(c1);
        for (int f = f0; f < f1; ++f) tm[f] = t;
    }
    int z0 = (int)ceilf(s_c[T_TOK - 1]);
    for (int f = z0 + tid; f < T_MEL; f += 256) tm[f] = T_TOK;   // invalid -> zeros
}

// ---- persistent fused: work-stealing conv tiles (units 0..511) + expand (512..1535) ----
__global__ __launch_bounds__(512, 4) void fused_kernel(
    const float* __restrict__ x, const short* __restrict__ wr,
    const float* __restrict__ cb, const float* __restrict__ g,
    const float* __restrict__ beta, const float* __restrict__ lw,
    const float* __restrict__ lb, const int* __restrict__ tn,
    const int* __restrict__ tokmap,
    float* __restrict__ m_out, float* __restrict__ xnew, float* __restrict__ acc,
    int* __restrict__ ctrs, float* __restrict__ mels)
{
    __shared__ char smem[XS_BYTES];      // 34816 B -> 4 blocks/CU
    __shared__ int s_unit;
    int tid = threadIdx.x;
    int lane = tid & 63;
    int wid = tid >> 6;

    for (;;) {
        __syncthreads();                 // protect smem + s_unit reuse
        if (tid == 0) s_unit = atomicAdd(&ctrs[0], 1);
        __syncthreads();
        int u = s_unit;
        if (u >= NUNITS) break;

        if (u >= NCONV) {
            // ------- expand unit: 128 frames; batched gathers + NT streaming stores ----
            int e = u - NCONV;
            int fbase = e * 128;
            int b = e >> 5;              // 32 units per batch row
            int* s_tok = (int*)smem;
            if (tid < 128) s_tok[tid] = tokmap[fbase + tid];
            __syncthreads();
            const float* xb = x + (size_t)b * T_TOK * H_DIM;
            f32x4* dst = (f32x4*)(xnew + (size_t)(fbase + wid * 16) * H_DIM);
            f32x4 zv = {0.f, 0.f, 0.f, 0.f};
#pragma unroll
            for (int half = 0; half < 2; ++half) {
                f32x4 v[8];
#pragma unroll
                for (int i = 0; i < 8; ++i) {    // 8 independent gathers in flight
                    int tok = s_tok[wid * 16 + half * 8 + i];
                    int tokc = min(tok, T_TOK - 1);
                    v[i] = ((const f32x4*)(xb + (size_t)tokc * H_DIM))[lane];
                    if (tok >= T_TOK) v[i] = zv;
                }
#pragma unroll
                for (int i = 0; i < 8; ++i)
                    __builtin_nontemporal_store(v[i], dst + (half * 8 + i) * 64 + lane);
            }
            continue;
        }

        // ------- conv tile: 64 t-rows x 256 h_out; 8 waves as 1M x 8N -------
        int b = u >> 4;
        int t0 = (u & 15) * BM;

        // stage x rows [t0-2, t0+66) as bf16, XOR-swizzled (512B rows)
        for (int i = tid; i < ROWS * 64; i += 512) {
            int row = i >> 6;
            int c4 = i & 63;
            int t = t0 - 2 + row;
            float4 v = make_float4(0.f, 0.f, 0.f, 0.f);
            if (t >= 0 && t < T_TOK)
                v = *reinterpret_cast<const float4*>(x + ((size_t)b * T_TOK + t) * H_DIM + c4 * 4);
            short4 h;
            h.x = f2bf(v.x); h.y = f2bf(v.y); h.z = f2bf(v.z); h.w = f2bf(v.w);
            int byte = row * 512 + c4 * 8;
            byte ^= (row & 7) << 4;
            *reinterpret_cast<short4*>(smem + byte) = h;
        }
        __syncthreads();

        const bf16x8* wf = reinterpret_cast<const bf16x8*>(wr);
        f32x4 zero = {0.f, 0.f, 0.f, 0.f};
        f32x4 acc_[4][2];
#pragma unroll
        for (int mi = 0; mi < 4; ++mi)
#pragma unroll
            for (int ni = 0; ni < 2; ++ni) acc_[mi][ni] = zero;

        int arow = lane & 15;            // A-fragment row within 16-chunk
        int ccol = (lane >> 4) * 16;     // byte offset of lane's 8-bf16 k-group
        int n16 = wid * 2;               // this wave's first 16-col fragment index

        bf16x8 bc[2], bn[2];
#pragma unroll
        for (int ni = 0; ni < 2; ++ni) bc[ni] = wf[(size_t)(n16 + ni) * 64 + lane];

        for (int s = 0; s < 40; ++s) {
            if (s < 39) {                // prefetch next step's B frags
#pragma unroll
                for (int ni = 0; ni < 2; ++ni)
                    bn[ni] = wf[(size_t)((s + 1) * 16 + n16 + ni) * 64 + lane];
            }
            int rb = arow + (s >> 3);    // staged row = t_loc + k
            int cbase = (s & 7) * 64 + ccol;
            bf16x8 a[4];
#pragma unroll
            for (int mi = 0; mi < 4; ++mi) {
                int rr = mi * 16 + rb;
                int by = (rr * 512 + cbase) ^ ((rr & 7) << 4);
                a[mi] = *reinterpret_cast<const bf16x8*>(smem + by);
            }
#pragma unroll
            for (int mi = 0; mi < 4; ++mi)
#pragma unroll
                for (int ni = 0; ni < 2; ++ni)
                    acc_[mi][ni] = __builtin_amdgcn_mfma_f32_16x16x32_bf16(a[mi], bc[ni], acc_[mi][ni], 0, 0, 0);
#pragma unroll
            for (int ni = 0; ni < 2; ++ni) bc[ni] = bn[ni];
        }

        // ---- fragment-local LN + ReLU + dot epilogue (overlays dead x-tile LDS) ----
        // D layout (m89): col = wid*32 + ni*16 + (lane&15), row = mi*16 + 4*(lane>>4)+reg
        __syncthreads();
        float* ps   = reinterpret_cast<float*>(smem);          // [64][8] row-sums
        float* pq   = ps + 512;                                // [64][8] row-sumsq
        float* pdot = pq + 512;                                // [64][8] dot partials
        float* mus  = pdot + 512;                              // [64]
        float* rss  = mus + 64;                                // [64]

        float cbv[2];
#pragma unroll
        for (int ni = 0; ni < 2; ++ni) cbv[ni] = cb[wid * 32 + ni * 16 + (lane & 15)];

#pragma unroll
        for (int mi = 0; mi < 4; ++mi)
#pragma unroll
            for (int rr = 0; rr < 4; ++rr) {
                float s = 0.f, qq = 0.f;
#pragma unroll
                for (int ni = 0; ni < 2; ++ni) {
                    float v = acc_[mi][ni][rr] + cbv[ni];
                    s += v; qq += v * v;
                }
#pragma unroll
                for (int m = 1; m < 16; m <<= 1) {
                    s += __shfl_xor(s, m);
                    qq += __shfl_xor(qq, m);
                }
                if ((lane & 15) == 0) {
                    int row = mi * 16 + (lane >> 4) * 4 + rr;
                    ps[row * 8 + wid] = s;
                    pq[row * 8 + wid] = qq;
                }
            }
        __syncthreads();
        if (tid < 64) {
            float S = 0.f, Q = 0.f;
#pragma unroll
            for (int w = 0; w < 8; ++w) { S += ps[tid * 8 + w]; Q += pq[tid * 8 + w]; }
            float mu = S * (1.f / 256.f);
            float var = Q * (1.f / 256.f) - mu * mu;
            mus[tid] = mu;
            rss[tid] = rsqrtf(var + 1e-5f);
        }
        __syncthreads();

        float gv[2], bv[2], lv[2];
#pragma unroll
        for (int ni = 0; ni < 2; ++ni) {
            int col = wid * 32 + ni * 16 + (lane & 15);
            gv[ni] = g[col]; bv[ni] = beta[col]; lv[ni] = lw[col];
        }
#pragma unroll
        for (int mi = 0; mi < 4; ++mi)
#pragma unroll
            for (int rr = 0; rr < 4; ++rr) {
                int row = mi * 16 + (lane >> 4) * 4 + rr;
                float mu = mus[row], rs = rss[row];
                float dt = 0.f;
#pragma unroll
                for (int ni = 0; ni < 2; ++ni) {
                    float v = acc_[mi][ni][rr] + cbv[ni];
                    float y = fmaxf((v - mu) * rs * gv[ni] + bv[ni], 0.f);
                    dt += y * lv[ni];
                }
#pragma unroll
                for (int m = 1; m < 16; m <<= 1) dt += __shfl_xor(dt, m);
                if ((lane & 15) == 0) pdot[row * 8 + wid] = dt;
            }
        __syncthreads();
        if (tid < 64) {
            float dot = lb[0];
#pragma unroll
            for (int w = 0; w < 8; ++w) dot += pdot[tid * 8 + w];
            int t = t0 + tid;
            float mv = (t < tn[b]) ? dot : 0.f;
            m_out[b * T_TOK + t] = mv;
            float e = (t < tn[b]) ? expf(mv) : 0.f;  // partial of mels_num_predicted
#pragma unroll
            for (int m = 1; m < 64; m <<= 1) e += __shfl_xor(e, m);
            if (tid == 0) atomicAdd(&acc[b], e);
        }
    }

    // ---- last block finalizes mels_num_predicted = float(int(acc[b])) ----
    __threadfence();
    if (tid == 0) {
        if (atomicAdd(&ctrs[1], 1) == (int)gridDim.x - 1) {
            for (int b = 0; b < B_SZ; ++b) {
                float v = atomicAdd(&acc[b], 0.f);   // coherent device-scope read
                mels[b] = (float)((int)v);
            }
        }
    }
}

extern "C" void kernel_launch(void* const* d_in, const int* in_sizes, int n_in,
                              void* d_out, int out_size, void* d_ws, size_t ws_size,
                              hipStream_t stream) {
    const float* x          = (const float*)d_in[0];
    const int*   token_nums = (const int*)d_in[1];
    const float* align      = (const float*)d_in[2];
    const int*   gt         = (const int*)d_in[3];
    // conv1 branch (d_in[4..7]) is dead in the reference
    const float* w2  = (const float*)d_in[8];
    const float* b2  = (const float*)d_in[9];
    const float* g2  = (const float*)d_in[10];
    const float* be2 = (const float*)d_in[11];
    const float* lw  = (const float*)d_in[12];
    const float* lb  = (const float*)d_in[13];

    float* out   = (float*)d_out;
    float* xnew  = out;                                        // [B, T_MEL, H]
    float* m_out = out + (size_t)B_SZ * T_MEL * H_DIM;         // [B, T_TOK]
    float* mels  = m_out + (size_t)B_SZ * T_TOK;               // [B]

    short* wr   = (short*)d_ws;                                // 640KB bf16 fragments
    float* acc  = (float*)((char*)d_ws + (size_t)40 * 16 * 64 * 8 * 2);   // [B]
    int* tokmap = (int*)((char*)acc + 128);                    // [B][T_MEL] int
    int* ctrs   = (int*)((char*)tokmap + (size_t)B_SZ * T_MEL * 4);       // [2]

    prep_kernel<<<192, 256, 0, stream>>>(w2, wr, align, gt, acc, tokmap, ctrs);
    fused_kernel<<<1024, 512, 0, stream>>>(x, wr, b2, g2, be2, lw, lb,
                                           token_nums, tokmap, m_out, xnew, acc,
                                           ctrs, mels);
}

// Round 10
// 66.023 us; speedup vs baseline: 4.0559x; 4.0559x over previous
//
#include <hip/hip_runtime.h>
#include <hip/hip_bf16.h>

#define B_SZ 32
#define T_TOK 1024
#define H_DIM 256
#define T_MEL 4096
#define K_SZ 5
#define BM 64
#define ROWS (BM + 4)          // 68 staged x rows
#define XS_BYTES (ROWS * 512)  // 34816
#define NCONV 512              // conv tile units (blocks 0..511)
#define NEXPB 512              // expand blocks (512..1023), 256 frames each

typedef __attribute__((ext_vector_type(8))) short bf16x8;
typedef __attribute__((ext_vector_type(4))) float f32x4;

__device__ inline short f2bf(float f) {
    __hip_bfloat16 h = __float2bfloat16(f);
    return *reinterpret_cast<short*>(&h);
}

// ---- prep: repack W (blocks 0..159) + scan+tokmap scatter (blocks 160..191) ----
// W repack: [H_out][H_in][K] f32 -> bf16 B-fragment order [s][n16][lane][j]
__global__ __launch_bounds__(256) void prep_kernel(const float* __restrict__ w,
                                                   short* __restrict__ wr,
                                                   const float* __restrict__ a,
                                                   const int* __restrict__ gt,
                                                   float* __restrict__ acc,
                                                   int* __restrict__ tokmap) {
    __shared__ float s_c[T_TOK];
    if (blockIdx.x < 160) {
        int idx = blockIdx.x * 256 + threadIdx.x;   // 40*16*64 threads
        int lane = idx & 63;
        int n = (idx >> 6) & 15;
        int s = idx >> 10;
        int k = s >> 3;
        int hi0 = (s & 7) * 32 + (lane >> 4) * 8;
        int ho = n * 16 + (lane & 15);
        short out[8];
#pragma unroll
        for (int j = 0; j < 8; ++j)
            out[j] = f2bf(w[(ho * H_DIM + hi0 + j) * K_SZ + k]);
        *reinterpret_cast<bf16x8*>(wr + (size_t)idx * 8) = *reinterpret_cast<bf16x8*>(out);
        return;
    }
    int b = blockIdx.x - 160;
    int tid = threadIdx.x;
    if (tid == 1) acc[b] = 0.f;                     // reset exp-sum accumulator
    ((float4*)s_c)[tid] = ((const float4*)(a + b * T_TOK))[tid];
    __syncthreads();
    if (tid == 0) {
        float c = 0.f;
        float lim = (float)gt[b];
        for (int t = 0; t < T_TOK; ++t) {           // matches np.cumsum order
            c += s_c[t];
            s_c[t] = fminf(c, lim);
        }
    }
    __syncthreads();
    // token t owns frames [ceil(c[t-1]), ceil(c[t]))  (contiguous partition)
    int* tm = tokmap + b * T_MEL;
    for (int t = tid; t < T_TOK; t += 256) {
        float c1 = s_c[t];
        float c0 = (t == 0) ? 0.f : s_c[t - 1];
        int f0 = (int)ceilf(c0);
        int f1 = (int)ceilf(c1);
        for (int f = f0; f < f1; ++f) tm[f] = t;
    }
    int z0 = (int)ceilf(s_c[T_TOK - 1]);
    for (int f = z0 + tid; f < T_MEL; f += 256) tm[f] = T_TOK;   // invalid -> zeros
}

// ---- fused, fully-resident static split: 1024 blocks = 256CU x 4 (LDS 34.8KB) ----
// blocks [0,512): conv tiles; [512,1024): expand 256 frames each. Both ranges
// stripe all 8 XCDs; each CU co-hosts ~2 conv + ~2 expand blocks (m114 overlap).
__global__ __launch_bounds__(512, 4) void fused_kernel(
    const float* __restrict__ x, const short* __restrict__ wr,
    const float* __restrict__ cb, const float* __restrict__ g,
    const float* __restrict__ beta, const float* __restrict__ lw,
    const float* __restrict__ lb, const int* __restrict__ tn,
    const int* __restrict__ tokmap,
    float* __restrict__ m_out, float* __restrict__ xnew, float* __restrict__ acc)
{
    __shared__ char smem[XS_BYTES];      // 34816 B -> 4 blocks/CU
    int tid = threadIdx.x;
    int lane = tid & 63;
    int wid = tid >> 6;

    if (blockIdx.x >= NCONV) {
        // ------- expand block: 256 frames; batched gathers + NT streaming stores ----
        int e = blockIdx.x - NCONV;      // 0..511
        int fbase = e * 256;
        int b = e >> 4;                  // 16 blocks per batch row
        int* s_tok = (int*)smem;
        if (tid < 256) s_tok[tid] = tokmap[fbase + tid];
        __syncthreads();
        const float* xb = x + (size_t)b * T_TOK * H_DIM;
        f32x4* dst = (f32x4*)(xnew + (size_t)(fbase + wid * 32) * H_DIM);
        f32x4 zv = {0.f, 0.f, 0.f, 0.f};
#pragma unroll
        for (int bt = 0; bt < 4; ++bt) {
            f32x4 v[8];
#pragma unroll
            for (int i = 0; i < 8; ++i) {        // 8 independent gathers in flight
                int tok = s_tok[wid * 32 + bt * 8 + i];
                int tokc = min(tok, T_TOK - 1);
                v[i] = ((const f32x4*)(xb + (size_t)tokc * H_DIM))[lane];
                if (tok >= T_TOK) v[i] = zv;
            }
#pragma unroll
            for (int i = 0; i < 8; ++i)
                __builtin_nontemporal_store(v[i], dst + (bt * 8 + i) * 64 + lane);
        }
        return;
    }

    // ------- conv tile: 64 t-rows x 256 h_out; 8 waves as 1M x 8N -------
    int b = blockIdx.x >> 4;
    int t0 = (blockIdx.x & 15) * BM;

    // stage x rows [t0-2, t0+66) as bf16, XOR-swizzled (512B rows)
    for (int i = tid; i < ROWS * 64; i += 512) {
        int row = i >> 6;
        int c4 = i & 63;
        int t = t0 - 2 + row;
        float4 v = make_float4(0.f, 0.f, 0.f, 0.f);
        if (t >= 0 && t < T_TOK)
            v = *reinterpret_cast<const float4*>(x + ((size_t)b * T_TOK + t) * H_DIM + c4 * 4);
        short4 h;
        h.x = f2bf(v.x); h.y = f2bf(v.y); h.z = f2bf(v.z); h.w = f2bf(v.w);
        int byte = row * 512 + c4 * 8;
        byte ^= (row & 7) << 4;
        *reinterpret_cast<short4*>(smem + byte) = h;
    }
    __syncthreads();

    const bf16x8* wf = reinterpret_cast<const bf16x8*>(wr);
    f32x4 zero = {0.f, 0.f, 0.f, 0.f};
    f32x4 acc_[4][2];
#pragma unroll
    for (int mi = 0; mi < 4; ++mi)
#pragma unroll
        for (int ni = 0; ni < 2; ++ni) acc_[mi][ni] = zero;

    int arow = lane & 15;            // A-fragment row within 16-chunk
    int ccol = (lane >> 4) * 16;     // byte offset of lane's 8-bf16 k-group
    int n16 = wid * 2;               // this wave's first 16-col fragment index

    bf16x8 bc[2], bn[2];
#pragma unroll
    for (int ni = 0; ni < 2; ++ni) bc[ni] = wf[(size_t)(n16 + ni) * 64 + lane];

    for (int s = 0; s < 40; ++s) {
        if (s < 39) {                // prefetch next step's B frags (no barrier needed)
#pragma unroll
            for (int ni = 0; ni < 2; ++ni)
                bn[ni] = wf[(size_t)((s + 1) * 16 + n16 + ni) * 64 + lane];
        }
        int rb = arow + (s >> 3);    // staged row = t_loc + k
        int cbase = (s & 7) * 64 + ccol;
        bf16x8 a[4];
#pragma unroll
        for (int mi = 0; mi < 4; ++mi) {
            int rr = mi * 16 + rb;
            int by = (rr * 512 + cbase) ^ ((rr & 7) << 4);
            a[mi] = *reinterpret_cast<const bf16x8*>(smem + by);
        }
#pragma unroll
        for (int mi = 0; mi < 4; ++mi)
#pragma unroll
            for (int ni = 0; ni < 2; ++ni)
                acc_[mi][ni] = __builtin_amdgcn_mfma_f32_16x16x32_bf16(a[mi], bc[ni], acc_[mi][ni], 0, 0, 0);
#pragma unroll
        for (int ni = 0; ni < 2; ++ni) bc[ni] = bn[ni];
    }

    // ---- fragment-local LN + ReLU + dot epilogue (overlays dead x-tile LDS) ----
    // D layout (m89): col = wid*32 + ni*16 + (lane&15), row = mi*16 + 4*(lane>>4)+reg
    __syncthreads();
    float* ps   = reinterpret_cast<float*>(smem);          // [64][8] row-sums
    float* pq   = ps + 512;                                // [64][8] row-sumsq
    float* pdot = pq + 512;                                // [64][8] dot partials
    float* mus  = pdot + 512;                              // [64]
    float* rss  = mus + 64;                                // [64]

    float cbv[2];
#pragma unroll
    for (int ni = 0; ni < 2; ++ni) cbv[ni] = cb[wid * 32 + ni * 16 + (lane & 15)];

#pragma unroll
    for (int mi = 0; mi < 4; ++mi)
#pragma unroll
        for (int rr = 0; rr < 4; ++rr) {
            float s = 0.f, qq = 0.f;
#pragma unroll
            for (int ni = 0; ni < 2; ++ni) {
                float v = acc_[mi][ni][rr] + cbv[ni];
                s += v; qq += v * v;
            }
#pragma unroll
            for (int m = 1; m < 16; m <<= 1) {
                s += __shfl_xor(s, m);
                qq += __shfl_xor(qq, m);
            }
            if ((lane & 15) == 0) {
                int row = mi * 16 + (lane >> 4) * 4 + rr;
                ps[row * 8 + wid] = s;
                pq[row * 8 + wid] = qq;
            }
        }
    __syncthreads();
    if (tid < 64) {
        float S = 0.f, Q = 0.f;
#pragma unroll
        for (int w = 0; w < 8; ++w) { S += ps[tid * 8 + w]; Q += pq[tid * 8 + w]; }
        float mu = S * (1.f / 256.f);
        float var = Q * (1.f / 256.f) - mu * mu;
        mus[tid] = mu;
        rss[tid] = rsqrtf(var + 1e-5f);
    }
    __syncthreads();

    float gv[2], bv[2], lv[2];
#pragma unroll
    for (int ni = 0; ni < 2; ++ni) {
        int col = wid * 32 + ni * 16 + (lane & 15);
        gv[ni] = g[col]; bv[ni] = beta[col]; lv[ni] = lw[col];
    }
#pragma unroll
    for (int mi = 0; mi < 4; ++mi)
#pragma unroll
        for (int rr = 0; rr < 4; ++rr) {
            int row = mi * 16 + (lane >> 4) * 4 + rr;
            float mu = mus[row], rs = rss[row];
            float dt = 0.f;
#pragma unroll
            for (int ni = 0; ni < 2; ++ni) {
                float v = acc_[mi][ni][rr] + cbv[ni];
                float y = fmaxf((v - mu) * rs * gv[ni] + bv[ni], 0.f);
                dt += y * lv[ni];
            }
#pragma unroll
            for (int m = 1; m < 16; m <<= 1) dt += __shfl_xor(dt, m);
            if ((lane & 15) == 0) pdot[row * 8 + wid] = dt;
        }
    __syncthreads();
    if (tid < 64) {
        float dot = lb[0];
#pragma unroll
        for (int w = 0; w < 8; ++w) dot += pdot[tid * 8 + w];
        int t = t0 + tid;
        float mv = (t < tn[b]) ? dot : 0.f;
        m_out[b * T_TOK + t] = mv;
        float e = (t < tn[b]) ? expf(mv) : 0.f;      // partial of mels_num_predicted
#pragma unroll
        for (int m = 1; m < 64; m <<= 1) e += __shfl_xor(e, m);
        if (tid == 0) atomicAdd(&acc[b], e);         // 32 distinct lines, 16 ops each
    }
}

// ---- finalize: mels_num_predicted = float(int(acc[b])) ----
__global__ __launch_bounds__(64) void finalize_kernel(const float* __restrict__ acc,
                                                      float* __restrict__ out) {
    int b = threadIdx.x;
    if (b < B_SZ) out[b] = (float)((int)acc[b]);
}

extern "C" void kernel_launch(void* const* d_in, const int* in_sizes, int n_in,
                              void* d_out, int out_size, void* d_ws, size_t ws_size,
                              hipStream_t stream) {
    const float* x          = (const float*)d_in[0];
    const int*   token_nums = (const int*)d_in[1];
    const float* align      = (const float*)d_in[2];
    const int*   gt         = (const int*)d_in[3];
    // conv1 branch (d_in[4..7]) is dead in the reference
    const float* w2  = (const float*)d_in[8];
    const float* b2  = (const float*)d_in[9];
    const float* g2  = (const float*)d_in[10];
    const float* be2 = (const float*)d_in[11];
    const float* lw  = (const float*)d_in[12];
    const float* lb  = (const float*)d_in[13];

    float* out   = (float*)d_out;
    float* xnew  = out;                                        // [B, T_MEL, H]
    float* m_out = out + (size_t)B_SZ * T_MEL * H_DIM;         // [B, T_TOK]
    float* mels  = m_out + (size_t)B_SZ * T_TOK;               // [B]

    short* wr   = (short*)d_ws;                                // 640KB bf16 fragments
    float* acc  = (float*)((char*)d_ws + (size_t)40 * 16 * 64 * 8 * 2);   // [B]
    int* tokmap = (int*)((char*)acc + 128);                    // [B][T_MEL] int

    prep_kernel<<<192, 256, 0, stream>>>(w2, wr, align, gt, acc, tokmap);
    fused_kernel<<<NCONV + NEXPB, 512, 0, stream>>>(x, wr, b2, g2, be2, lw, lb,
                                                    token_nums, tokmap, m_out, xnew, acc);
    finalize_kernel<<<1, 64, 0, stream>>>(acc, mels);
}